// Round 23
// baseline (88.287 us; speedup 1.0000x reference)
//
#include <hip/hip_runtime.h>

#define N    1024
#define HD   64
#define MD   32
#define BLK  256        // k_p0 block
#define BLKP 1024       // pair block: 16 waves, 4 rows/block, grid 256
#define WROW (2 * HD + 1)   // 129, w_msg row stride

typedef _Float16 h2 __attribute__((ext_vector_type(2)));

__device__ __forceinline__ float dot2(h2 a, h2 b, float c)
{
#if __has_builtin(__builtin_amdgcn_fdot2)
    return __builtin_amdgcn_fdot2(a, b, c, false);
#else
    return c + (float)a[0] * (float)b[0] + (float)a[1] * (float)b[1];
#endif
}
__device__ __forceinline__ h2 pack2(float x, float y)
{
    h2 r; r[0] = (_Float16)x; r[1] = (_Float16)y; return r;
}

// ---------------------------------------------------------------------------
// P0: h0 = feat + posenc; A1/B1 projections (A also in f16). 1 block / 4 rows.
// ---------------------------------------------------------------------------
__global__ __launch_bounds__(BLK) void k_p0(const float* __restrict__ feat,
                                            const float* __restrict__ wmsg,
                                            const float* __restrict__ bmsg,
                                            float* __restrict__ h0,
                                            float* __restrict__ A,
                                            float* __restrict__ Bb,
                                            _Float16* __restrict__ Ah)
{
    __shared__ float scr[4160 + 4 * HD];
    const int tid = threadIdx.x;
    const int n0  = blockIdx.x * 4;

    for (int u = tid; u < MD * WROW; u += BLK) scr[u] = wmsg[u];   // 4128 floats
    float* hrow = scr + 4160;
    {
        const int n = n0 + (tid >> 6), d = tid & 63;
        const float div = expf((float)(d & ~1) * (-9.210340371976184f / 64.0f));
        const float ang = (float)n * div;
        const float pe  = (d & 1) ? cosf(ang) : sinf(ang);
        const float hv  = feat[n * HD + d] + pe;
        h0[n * HD + d] = hv;
        hrow[tid] = hv;
    }
    __syncthreads();
    if (tid < 4 * MD) {
        const int nl = tid >> 5, m = tid & 31;
        const float* wa = scr + m * WROW;          // stride 129: conflict-free
        const float* hr = hrow + nl * HD;
        float sa = 0.f, sb = bmsg[m];
#pragma unroll
        for (int c = 0; c < HD; c++) {
            const float hv = hr[c];
            sa = fmaf(hv, wa[c], sa);
            sb = fmaf(hv, wa[HD + c], sb);
        }
        const int n = n0 + nl;
        A[n * MD + m]  = sa;
        Bb[n * MD + m] = sb;
        Ah[n * MD + m] = (_Float16)sa;
    }
}

// ---------------------------------------------------------------------------
// Pair kernel v3c: one block (1024 thr = 16 waves) per 4 rows
// {bb, bb+256, bb+512, bb+768}; grid 256 -> 1 block/CU, 4 waves/SIMD.
// amdgpu_waves_per_eu(4,4): clamps allocator occupancy target to EXACTLY
// 4 waves/EU -> 128-VGPR budget. (R21/R22: default target 8 waves/EU gave a
// 64-VGPR cap -> 7.2 MB scratch spill per dispatch, 41us. launch_bounds'
// 2nd arg is only a MINIMUM, so it could not stop the 8-wave target.)
// Single rd table: rd[j] = (rA0, rA1, rA2, pack2(d2_0, d2_1));
// ud2[j] = pack2(d2_2, d2_3). Row-r vectors reconstructed: r_r = rA + dx_r.
// Lane map: kq = lane&3 owns k = kq*8..+7 (one uint4 A-load feeds 4 rows);
// jslot = lane>>2; wave owns 64 j -> 4 main-loop iterations (unroll 2 to
// bound in-flight-load register pressure under the 128 cap).
// ---------------------------------------------------------------------------
template<int LAYER1>
__global__ __attribute__((amdgpu_waves_per_eu(4, 4)))
__launch_bounds__(BLKP) void k_pair(
    const float* __restrict__ xsrc, const float* __restrict__ Aap,
    const _Float16* __restrict__ Ahp, const float* __restrict__ Bbp,
    const float* __restrict__ wmsg, const float* __restrict__ wpos,
    const float* __restrict__ bpos, float* __restrict__ xout,
    const float* __restrict__ h0, const float* __restrict__ wf,
    const float* __restrict__ bf, const float* __restrict__ wmsg2,
    const float* __restrict__ bmsg2, float* __restrict__ A2,
    float* __restrict__ B2, _Float16* __restrict__ A2h)
{
    const int tid   = threadIdx.x;
    const int wid   = tid >> 6;         // 0..15
    const int lane  = tid & 63;
    const int kq    = lane & 3;         // owns k = kq*8 .. kq*8+7
    const int jslot = lane >> 2;        // 0..15

    __shared__ float  sbuf[6848];       // 27.4 KB: rd(4096) | ud2(1024) | tail scr
    __shared__ float  sxacc[16][3];
    __shared__ float  vacc[16][4][3];
    __shared__ float  msl[LAYER1 ? 16 : 1][4][MD];   // 8 KB only in layer 1
    __shared__ float  SxL[3];
    __shared__ float  msF[4][MD];
    __shared__ float  h0r[4][HD];
    __shared__ float  h1r[4][HD];
    float4*   rd  = (float4*)sbuf;
    unsigned* ud2 = (unsigned*)(sbuf + 4096);

    const int bb = blockIdx.x;
    const int irow[4] = {bb, bb + 256, bb + 512, bb + 768};

    float xi[4][3], dx[4][3];
#pragma unroll
    for (int r = 0; r < 4; r++)
#pragma unroll
        for (int c = 0; c < 3; c++) xi[r][c] = xsrc[irow[r] * 3 + c];
#pragma unroll
    for (int r = 0; r < 4; r++)
#pragma unroll
        for (int c = 0; c < 3; c++) dx[r][c] = xi[0][c] - xi[r][c];   // dx[0]=0

    // ---- prologue: stage rd + ud2 (one j per thread); Sx partial ----
    {
        const int j = tid;
        const float xj0 = xsrc[j * 3 + 0];
        const float xj1 = xsrc[j * 3 + 1];
        const float xj2 = xsrc[j * 3 + 2];
        float sx0 = xj0, sx1 = xj1, sx2 = xj2;
        const float rA0 = xj0 - xi[0][0];
        const float rA1 = xj1 - xi[0][1];
        const float rA2 = xj2 - xi[0][2];
        float d2v[4];
#pragma unroll
        for (int r = 0; r < 4; r++) {
            const float r0 = rA0 + dx[r][0];
            const float r1 = rA1 + dx[r][1];
            const float r2 = rA2 + dx[r][2];
            d2v[r] = fmaf(r0, r0, fmaf(r1, r1, r2 * r2));
        }
        rd[j]  = make_float4(rA0, rA1, rA2,
                             __builtin_bit_cast(float, pack2(d2v[0], d2v[1])));
        ud2[j] = __builtin_bit_cast(unsigned, pack2(d2v[2], d2v[3]));
#pragma unroll
        for (int off = 32; off > 0; off >>= 1) {
            sx0 += __shfl_xor(sx0, off);
            sx1 += __shfl_xor(sx1, off);
            sx2 += __shfl_xor(sx2, off);
        }
        if (lane == 0) { sxacc[wid][0] = sx0; sxacc[wid][1] = sx1; sxacc[wid][2] = sx2; }
    }
    __syncthreads();                       // rd/ud2 + sx partials ready
    if (tid == 0) {
        float s0 = 0.f, s1 = 0.f, s2 = 0.f;
#pragma unroll
        for (int w = 0; w < 16; w++) { s0 += sxacc[w][0]; s1 += sxacc[w][1]; s2 += sxacc[w][2]; }
        SxL[0] = s0; SxL[1] = s1; SxL[2] = s2;
    }

    // ---- per-lane packed weights for the 8 owned k's ----
    h2 bi[4][4], wpx[4], wpy[4], wpz[4], wd[4];
#pragma unroll
    for (int r = 0; r < 4; r++) {
        const float4 b0 = *(const float4*)(Bbp + irow[r] * MD + kq * 8);
        const float4 b1 = *(const float4*)(Bbp + irow[r] * MD + kq * 8 + 4);
        bi[r][0] = pack2(b0.x, b0.y); bi[r][1] = pack2(b0.z, b0.w);
        bi[r][2] = pack2(b1.x, b1.y); bi[r][3] = pack2(b1.z, b1.w);
    }
    {
        const float4 px0 = *(const float4*)(wpos + kq * 8);
        const float4 px1 = *(const float4*)(wpos + kq * 8 + 4);
        const float4 py0 = *(const float4*)(wpos + MD + kq * 8);
        const float4 py1 = *(const float4*)(wpos + MD + kq * 8 + 4);
        const float4 pz0 = *(const float4*)(wpos + 2 * MD + kq * 8);
        const float4 pz1 = *(const float4*)(wpos + 2 * MD + kq * 8 + 4);
        wpx[0] = pack2(px0.x, px0.y); wpx[1] = pack2(px0.z, px0.w);
        wpx[2] = pack2(px1.x, px1.y); wpx[3] = pack2(px1.z, px1.w);
        wpy[0] = pack2(py0.x, py0.y); wpy[1] = pack2(py0.z, py0.w);
        wpy[2] = pack2(py1.x, py1.y); wpy[3] = pack2(py1.z, py1.w);
        wpz[0] = pack2(pz0.x, pz0.y); wpz[1] = pack2(pz0.z, pz0.w);
        wpz[2] = pack2(pz1.x, pz1.y); wpz[3] = pack2(pz1.z, pz1.w);
#pragma unroll
        for (int t = 0; t < 4; t++)
            wd[t] = pack2(wmsg[(kq * 8 + 2 * t) * WROW + 2 * HD],
                          wmsg[(kq * 8 + 2 * t + 1) * WROW + 2 * HD]);
    }
    const h2 hz = pack2(0.f, 0.f);

    float acc[4][3];
    h2 ms[4][4];
#pragma unroll
    for (int r = 0; r < 4; r++) {
        acc[r][0] = acc[r][1] = acc[r][2] = 0.f;
        ms[r][0] = ms[r][1] = ms[r][2] = ms[r][3] = hz;
    }

    const int jb = wid * 64;               // 64 j per wave
#pragma unroll 2
    for (int it = 0; it < 4; it++) {
        const int j = jb + it * 16 + jslot;
        const uint4 au = *(const uint4*)(Ahp + j * MD + kq * 8);  // feeds 4 rows
        h2 a[4];
        a[0] = __builtin_bit_cast(h2, au.x); a[1] = __builtin_bit_cast(h2, au.y);
        a[2] = __builtin_bit_cast(h2, au.z); a[3] = __builtin_bit_cast(h2, au.w);
        const float4 f = rd[j];            // 4-way broadcast per address
        const unsigned u23 = ud2[j];
        const h2 dd01 = __builtin_bit_cast(h2, f.w);
        const h2 dd23 = __builtin_bit_cast(h2, u23);
        h2 d2s[4];
        d2s[0] = __builtin_shufflevector(dd01, dd01, 0, 0);
        d2s[1] = __builtin_shufflevector(dd01, dd01, 1, 1);
        d2s[2] = __builtin_shufflevector(dd23, dd23, 0, 0);
        d2s[3] = __builtin_shufflevector(dd23, dd23, 1, 1);

#pragma unroll
        for (int r = 0; r < 4; r++) {
            const float r0 = (r == 0) ? f.x : f.x + dx[r][0];
            const float r1 = (r == 0) ? f.y : f.y + dx[r][1];
            const float r2 = (r == 0) ? f.z : f.z + dx[r][2];
            h2 m[4];
#pragma unroll
            for (int t = 0; t < 4; t++) {
                m[t] = __builtin_elementwise_max(d2s[r] * wd[t] + (a[t] + bi[r][t]), hz);
                if (LAYER1) ms[r][t] += m[t];
            }
            const float sx = dot2(m[3], wpx[3], dot2(m[2], wpx[2], dot2(m[1], wpx[1], dot2(m[0], wpx[0], 0.f))));
            const float sy = dot2(m[3], wpy[3], dot2(m[2], wpy[2], dot2(m[1], wpy[1], dot2(m[0], wpy[0], 0.f))));
            const float sz = dot2(m[3], wpz[3], dot2(m[2], wpz[2], dot2(m[1], wpz[1], dot2(m[0], wpz[0], 0.f))));
            acc[r][0] = fmaf(sx, r0, acc[r][0]);
            acc[r][1] = fmaf(sy, r1, acc[r][1]);
            acc[r][2] = fmaf(sz, r2, acc[r][2]);
        }
    }

    // ---- reduce acc across 64 lanes (sums jslot and kq partials) ----
#pragma unroll
    for (int off = 32; off > 0; off >>= 1)
#pragma unroll
        for (int r = 0; r < 4; r++) {
            acc[r][0] += __shfl_xor(acc[r][0], off);
            acc[r][1] += __shfl_xor(acc[r][1], off);
            acc[r][2] += __shfl_xor(acc[r][2], off);
        }
    if (LAYER1) {
        // reduce msum over the 16 jslots (lane bits 2..5), packed h2
#pragma unroll
        for (int off = 4; off <= 32; off <<= 1)
#pragma unroll
            for (int r = 0; r < 4; r++)
#pragma unroll
                for (int t = 0; t < 4; t++) {
                    const int v = __shfl_xor(__builtin_bit_cast(int, ms[r][t]), off);
                    ms[r][t] += __builtin_bit_cast(h2, v);
                }
    }
    if (lane == 0)
#pragma unroll
        for (int r = 0; r < 4; r++) {
            vacc[wid][r][0] = acc[r][0];
            vacc[wid][r][1] = acc[r][1];
            vacc[wid][r][2] = acc[r][2];
        }
    if (LAYER1 && jslot == 0)
#pragma unroll
        for (int r = 0; r < 4; r++)
#pragma unroll
            for (int t = 0; t < 4; t++) {
                msl[wid][r][kq * 8 + 2 * t]     = (float)ms[r][t][0];
                msl[wid][r][kq * 8 + 2 * t + 1] = (float)ms[r][t][1];
            }
    __syncthreads();                       // epilogue data ready

    if (tid < 12) {                        // parallel x-out: thread = (rr, c)
        const int rr = tid / 3, c = tid - rr * 3;
        float a = 0.f;
#pragma unroll
        for (int w = 0; w < 16; w++) a += vacc[w][rr][c];
        const int i = irow[rr];
        const float x0 = xi[rr][c];
        xout[i * 3 + c] = x0 + (a + bpos[c] * (SxL[c] - (float)N * x0)) * (1.0f / 1023.0f);
    }

    if (LAYER1) {
        // ---- fused h-update + layer-2 A/B projections for the 4 rows ----
        float* scr = sbuf;                 // 6848 floats free after main loop
        if (tid < 4 * MD) {                // msum rows with diagonal correction
            const int row = tid >> 5, k = tid & 31;
            const int i = irow[row];
            float s = 0.f;
#pragma unroll
            for (int w = 0; w < 16; w++) s += msl[w][row][k];
            s -= fmaxf(Aap[i * MD + k] + Bbp[i * MD + k], 0.f);   // d2=0 at j==i
            msF[row][k] = s;
        }
        for (int u = tid; u < HD * (HD + MD); u += BLKP) {         // stage wf
            const int o = u / (HD + MD), c = u - o * (HD + MD);
            scr[o * 97 + c] = wf[u];       // max 63*97+95 = 6206 < 6848
        }
        if (tid < 4 * HD) {
            const int row = tid >> 6, d = tid & 63;
            h0r[row][d] = h0[irow[row] * HD + d];
        }
        __syncthreads();
        if (tid < 4 * HD) {                // h1 rows (64 outputs x 4 rows)
            const int row = tid >> 6, o = tid & 63;
            const float* w = scr + o * 97;
            float s = bf[o];
#pragma unroll
            for (int c = 0; c < HD; c++) s = fmaf(h0r[row][c], w[c], s);
#pragma unroll
            for (int k = 0; k < MD; k++) s = fmaf(msF[row][k], w[HD + k], s);
            h1r[row][o] = fmaxf(s, 0.f);
        }
        __syncthreads();
        for (int u = tid; u < MD * WROW; u += BLKP) scr[u] = wmsg2[u];  // 4128 < 6848
        __syncthreads();
        if (tid < 4 * MD) {                // A2/B2 rows (+ f16 copy of A2)
            const int row = tid >> 5, m = tid & 31;
            const float* wa = scr + m * WROW;
            const float* hr = h1r[row];
            float sa = 0.f, sb = bmsg2[m];
#pragma unroll
            for (int c = 0; c < HD; c++) {
                const float hv = hr[c];
                sa = fmaf(hv, wa[c], sa);
                sb = fmaf(hv, wa[HD + c], sb);
            }
            const int i = irow[row];
            A2[i * MD + m]  = sa;
            B2[i * MD + m]  = sb;
            A2h[i * MD + m] = (_Float16)sa;
        }
    }
}

// ---------------------------------------------------------------------------
extern "C" void kernel_launch(void* const* d_in, const int* in_sizes, int n_in,
                              void* d_out, int out_size, void* d_ws, size_t ws_size,
                              hipStream_t stream)
{
    const float* pos     = (const float*)d_in[0];
    const float* feat    = (const float*)d_in[1];
    const float* w_msg1  = (const float*)d_in[3];
    const float* b_msg1  = (const float*)d_in[4];
    const float* w_pos1  = (const float*)d_in[5];
    const float* b_pos1  = (const float*)d_in[6];
    const float* w_feat1 = (const float*)d_in[7];
    const float* b_feat1 = (const float*)d_in[8];
    const float* w_msg2  = (const float*)d_in[9];
    const float* b_msg2  = (const float*)d_in[10];
    const float* w_pos2  = (const float*)d_in[11];
    const float* b_pos2  = (const float*)d_in[12];

    float* ws  = (float*)d_ws;
    float* h0  = ws;                 // N*HD
    float* A1  = h0  + N * HD;       // N*MD
    float* B1  = A1  + N * MD;
    float* x1  = B1  + N * MD;       // N*4 (padded)
    float* A2  = x1  + N * 4;
    float* B2  = A2  + N * MD;
    _Float16* Ah1 = (_Float16*)(B2 + N * MD);      // N*MD f16
    _Float16* Ah2 = Ah1 + N * MD;                  // N*MD f16

    k_p0<<<N / 4, BLK, 0, stream>>>(feat, w_msg1, b_msg1, h0, A1, B1, Ah1);
    k_pair<1><<<N / 4, BLKP, 0, stream>>>(pos, A1, Ah1, B1, w_msg1, w_pos1, b_pos1, x1,
                                          h0, w_feat1, b_feat1, w_msg2, b_msg2,
                                          A2, B2, Ah2);
    k_pair<0><<<N / 4, BLKP, 0, stream>>>(x1, A2, Ah2, B2, w_msg2, w_pos2, b_pos2,
                                          (float*)d_out,
                                          nullptr, nullptr, nullptr, nullptr,
                                          nullptr, nullptr, nullptr, nullptr);
}

// Round 24
// 33.634 us; speedup vs baseline: 2.6249x; 2.6249x over previous
//
#include <hip/hip_runtime.h>

#define N    1024
#define HD   64
#define MD   32
#define BLK  256        // k_p0 block
#define BLKP 512        // pair-kernel block: 8 waves
#define WROW (2 * HD + 1)   // 129, w_msg row stride

typedef _Float16 h2 __attribute__((ext_vector_type(2)));

__device__ __forceinline__ float dot2(h2 a, h2 b, float c)
{
#if __has_builtin(__builtin_amdgcn_fdot2)
    return __builtin_amdgcn_fdot2(a, b, c, false);
#else
    return c + (float)a[0] * (float)b[0] + (float)a[1] * (float)b[1];
#endif
}
__device__ __forceinline__ h2 pack2(float x, float y)
{
    h2 r; r[0] = (_Float16)x; r[1] = (_Float16)y; return r;
}

// ---------------------------------------------------------------------------
// P0: h0 = feat + posenc; A1/B1 projections (A also in f16). 1 block / 4 rows.
// ---------------------------------------------------------------------------
__global__ __launch_bounds__(BLK) void k_p0(const float* __restrict__ feat,
                                            const float* __restrict__ wmsg,
                                            const float* __restrict__ bmsg,
                                            float* __restrict__ h0,
                                            float* __restrict__ A,
                                            float* __restrict__ Bb,
                                            _Float16* __restrict__ Ah)
{
    __shared__ float scr[4160 + 4 * HD];
    const int tid = threadIdx.x;
    const int n0  = blockIdx.x * 4;

    for (int u = tid; u < MD * WROW; u += BLK) scr[u] = wmsg[u];   // 4128 floats
    float* hrow = scr + 4160;
    {
        const int n = n0 + (tid >> 6), d = tid & 63;
        const float div = expf((float)(d & ~1) * (-9.210340371976184f / 64.0f));
        const float ang = (float)n * div;
        const float pe  = (d & 1) ? cosf(ang) : sinf(ang);
        const float hv  = feat[n * HD + d] + pe;
        h0[n * HD + d] = hv;
        hrow[tid] = hv;
    }
    __syncthreads();
    if (tid < 4 * MD) {
        const int nl = tid >> 5, m = tid & 31;
        const float* wa = scr + m * WROW;          // stride 129: conflict-free
        const float* hr = hrow + nl * HD;
        float sa = 0.f, sb = bmsg[m];
#pragma unroll
        for (int c = 0; c < HD; c++) {
            const float hv = hr[c];
            sa = fmaf(hv, wa[c], sa);
            sb = fmaf(hv, wa[HD + c], sb);
        }
        const int n = n0 + nl;
        A[n * MD + m]  = sa;
        Bb[n * MD + m] = sb;
        Ah[n * MD + m] = (_Float16)sa;
    }
}

// ---------------------------------------------------------------------------
// Pair kernel v2 (R20, best known: 33.7us total): one block (512 thr = 8
// waves) per row-pair (iA, iB=iA+N/2).
// SINGLE rd table: rd[j] = (rA0, rA1, rA2, pack2(d2A, d2B));
// rB reconstructed in-loop: rB = rA + (xiA - xiB).
// Lane map: kq = lane&3 owns k = kq*8..+7 (one uint4 A-load);
// jslot = lane>>2 (16 j per wave-iter) -> 8 main-loop iterations.
// sbuf (6848 floats) aliases rd (4096 floats) and the LAYER1 tail scratch.
// ---------------------------------------------------------------------------
template<int LAYER1>
__global__ __launch_bounds__(BLKP) void k_pair(
    const float* __restrict__ xsrc, const float* __restrict__ Aap,
    const _Float16* __restrict__ Ahp, const float* __restrict__ Bbp,
    const float* __restrict__ wmsg, const float* __restrict__ wpos,
    const float* __restrict__ bpos, float* __restrict__ xout,
    const float* __restrict__ h0, const float* __restrict__ wf,
    const float* __restrict__ bf, const float* __restrict__ wmsg2,
    const float* __restrict__ bmsg2, float* __restrict__ A2,
    float* __restrict__ B2, _Float16* __restrict__ A2h)
{
    const int tid   = threadIdx.x;
    const int wid   = tid >> 6;         // 0..7
    const int lane  = tid & 63;
    const int kq    = lane & 3;         // owns k = kq*8 .. kq*8+7
    const int jslot = lane >> 2;        // 0..15

    __shared__ float  sbuf[6848];       // 27.4 KB: rd[N] (16 KB) | tail scr
    __shared__ float  wacc[8][8];
    __shared__ float  msAl[8][MD];
    __shared__ float  msBl[8][MD];
    __shared__ float  SxL[3];
    __shared__ float  msF[2][MD];
    __shared__ float  h0r[2][HD];
    __shared__ float  h1r[2][HD];
    float4* rd = (float4*)sbuf;

    const int iA = blockIdx.x, iB = blockIdx.x + N / 2;
    const float xiA0 = xsrc[iA * 3 + 0], xiA1 = xsrc[iA * 3 + 1], xiA2 = xsrc[iA * 3 + 2];
    const float xiB0 = xsrc[iB * 3 + 0], xiB1 = xsrc[iB * 3 + 1], xiB2 = xsrc[iB * 3 + 2];
    const float dx0 = xiA0 - xiB0, dx1 = xiA1 - xiB1, dx2 = xiA2 - xiB2;  // rB = rA + dx

    // ---- stage single rd table (rA + packed d2A,d2B); Sx partial ----
    float sx0 = 0.f, sx1 = 0.f, sx2 = 0.f;
#pragma unroll
    for (int q = 0; q < N / BLKP; q++) {
        const int j = q * BLKP + tid;
        const float xj0 = xsrc[j * 3 + 0];
        const float xj1 = xsrc[j * 3 + 1];
        const float xj2 = xsrc[j * 3 + 2];
        sx0 += xj0; sx1 += xj1; sx2 += xj2;
        const float a0 = xj0 - xiA0, a1 = xj1 - xiA1, a2 = xj2 - xiA2;
        const float d2A = fmaf(a0, a0, fmaf(a1, a1, a2 * a2));
        const float b0 = xj0 - xiB0, b1 = xj1 - xiB1, b2 = xj2 - xiB2;
        const float d2B = fmaf(b0, b0, fmaf(b1, b1, b2 * b2));
        rd[j] = make_float4(a0, a1, a2, __builtin_bit_cast(float, pack2(d2A, d2B)));
    }
#pragma unroll
    for (int off = 32; off > 0; off >>= 1) {
        sx0 += __shfl_xor(sx0, off);
        sx1 += __shfl_xor(sx1, off);
        sx2 += __shfl_xor(sx2, off);
    }
    if (lane == 0) { wacc[wid][0] = sx0; wacc[wid][1] = sx1; wacc[wid][2] = sx2; }
    __syncthreads();                       // rd table + sx partials ready
    if (tid == 0) {
        float s0 = 0.f, s1 = 0.f, s2 = 0.f;
#pragma unroll
        for (int w = 0; w < 8; w++) { s0 += wacc[w][0]; s1 += wacc[w][1]; s2 += wacc[w][2]; }
        SxL[0] = s0; SxL[1] = s1; SxL[2] = s2;
    }

    // ---- per-lane packed weights for the 8 owned k's ----
    h2 biA[4], biB[4], wpx[4], wpy[4], wpz[4], wd[4];
    {
        const float4 bA0 = *(const float4*)(Bbp + iA * MD + kq * 8);
        const float4 bA1 = *(const float4*)(Bbp + iA * MD + kq * 8 + 4);
        const float4 bB0 = *(const float4*)(Bbp + iB * MD + kq * 8);
        const float4 bB1 = *(const float4*)(Bbp + iB * MD + kq * 8 + 4);
        biA[0] = pack2(bA0.x, bA0.y); biA[1] = pack2(bA0.z, bA0.w);
        biA[2] = pack2(bA1.x, bA1.y); biA[3] = pack2(bA1.z, bA1.w);
        biB[0] = pack2(bB0.x, bB0.y); biB[1] = pack2(bB0.z, bB0.w);
        biB[2] = pack2(bB1.x, bB1.y); biB[3] = pack2(bB1.z, bB1.w);
        const float4 px0 = *(const float4*)(wpos + kq * 8);
        const float4 px1 = *(const float4*)(wpos + kq * 8 + 4);
        const float4 py0 = *(const float4*)(wpos + MD + kq * 8);
        const float4 py1 = *(const float4*)(wpos + MD + kq * 8 + 4);
        const float4 pz0 = *(const float4*)(wpos + 2 * MD + kq * 8);
        const float4 pz1 = *(const float4*)(wpos + 2 * MD + kq * 8 + 4);
        wpx[0] = pack2(px0.x, px0.y); wpx[1] = pack2(px0.z, px0.w);
        wpx[2] = pack2(px1.x, px1.y); wpx[3] = pack2(px1.z, px1.w);
        wpy[0] = pack2(py0.x, py0.y); wpy[1] = pack2(py0.z, py0.w);
        wpy[2] = pack2(py1.x, py1.y); wpy[3] = pack2(py1.z, py1.w);
        wpz[0] = pack2(pz0.x, pz0.y); wpz[1] = pack2(pz0.z, pz0.w);
        wpz[2] = pack2(pz1.x, pz1.y); wpz[3] = pack2(pz1.z, pz1.w);
#pragma unroll
        for (int t = 0; t < 4; t++)
            wd[t] = pack2(wmsg[(kq * 8 + 2 * t) * WROW + 2 * HD],
                          wmsg[(kq * 8 + 2 * t + 1) * WROW + 2 * HD]);
    }
    const h2 hz = pack2(0.f, 0.f);

    float aA0 = 0.f, aA1 = 0.f, aA2 = 0.f, aB0 = 0.f, aB1 = 0.f, aB2 = 0.f;
    h2 msA[4] = {hz, hz, hz, hz}, msB[4] = {hz, hz, hz, hz};

    const int jb = wid * (N / 8);          // 128 j per wave
#pragma unroll 8
    for (int it = 0; it < 8; it++) {
        const int j = jb + it * 16 + jslot;
        const uint4 au = *(const uint4*)(Ahp + j * MD + kq * 8);  // 8 f16 = 16B/lane
        h2 a[4];
        a[0] = __builtin_bit_cast(h2, au.x); a[1] = __builtin_bit_cast(h2, au.y);
        a[2] = __builtin_bit_cast(h2, au.z); a[3] = __builtin_bit_cast(h2, au.w);
        const float4 f = rd[j];            // 4-way broadcast per address
        const h2 dd = __builtin_bit_cast(h2, f.w);
        const h2 dA = __builtin_shufflevector(dd, dd, 0, 0);   // op_sel splat
        const h2 dB = __builtin_shufflevector(dd, dd, 1, 1);
        const float rB0 = f.x + dx0, rB1 = f.y + dx1, rB2 = f.z + dx2;

        h2 mA[4], mB[4];
#pragma unroll
        for (int t = 0; t < 4; t++) {
            mA[t] = __builtin_elementwise_max(dA * wd[t] + (a[t] + biA[t]), hz);
            mB[t] = __builtin_elementwise_max(dB * wd[t] + (a[t] + biB[t]), hz);
            if (LAYER1) { msA[t] += mA[t]; msB[t] += mB[t]; }
        }
        const float sAx = dot2(mA[3], wpx[3], dot2(mA[2], wpx[2], dot2(mA[1], wpx[1], dot2(mA[0], wpx[0], 0.f))));
        const float sAy = dot2(mA[3], wpy[3], dot2(mA[2], wpy[2], dot2(mA[1], wpy[1], dot2(mA[0], wpy[0], 0.f))));
        const float sAz = dot2(mA[3], wpz[3], dot2(mA[2], wpz[2], dot2(mA[1], wpz[1], dot2(mA[0], wpz[0], 0.f))));
        const float sBx = dot2(mB[3], wpx[3], dot2(mB[2], wpx[2], dot2(mB[1], wpx[1], dot2(mB[0], wpx[0], 0.f))));
        const float sBy = dot2(mB[3], wpy[3], dot2(mB[2], wpy[2], dot2(mB[1], wpy[1], dot2(mB[0], wpy[0], 0.f))));
        const float sBz = dot2(mB[3], wpz[3], dot2(mB[2], wpz[2], dot2(mB[1], wpz[1], dot2(mB[0], wpz[0], 0.f))));
        aA0 = fmaf(sAx, f.x, aA0);
        aA1 = fmaf(sAy, f.y, aA1);
        aA2 = fmaf(sAz, f.z, aA2);
        aB0 = fmaf(sBx, rB0, aB0);
        aB1 = fmaf(sBy, rB1, aB1);
        aB2 = fmaf(sBz, rB2, aB2);
    }

    // ---- reduce acc across 64 lanes (sums jslot and kq partials) ----
#pragma unroll
    for (int off = 32; off > 0; off >>= 1) {
        aA0 += __shfl_xor(aA0, off); aA1 += __shfl_xor(aA1, off); aA2 += __shfl_xor(aA2, off);
        aB0 += __shfl_xor(aB0, off); aB1 += __shfl_xor(aB1, off); aB2 += __shfl_xor(aB2, off);
    }
    float msAf[8], msBf[8];
    if (LAYER1) {
#pragma unroll
        for (int t = 0; t < 4; t++) {
            msAf[2 * t] = (float)msA[t][0]; msAf[2 * t + 1] = (float)msA[t][1];
            msBf[2 * t] = (float)msB[t][0]; msBf[2 * t + 1] = (float)msB[t][1];
        }
        // reduce msum over the 16 jslots (lane bits 2..5)
#pragma unroll
        for (int off = 4; off <= 32; off <<= 1) {
#pragma unroll
            for (int t = 0; t < 8; t++) {
                msAf[t] += __shfl_xor(msAf[t], off);
                msBf[t] += __shfl_xor(msBf[t], off);
            }
        }
    }
    __syncthreads();                       // wacc consumed into SxL; reusable
    if (lane == 0) {
        wacc[wid][0] = aA0; wacc[wid][1] = aA1; wacc[wid][2] = aA2;
        wacc[wid][3] = aB0; wacc[wid][4] = aB1; wacc[wid][5] = aB2;
    }
    if (LAYER1 && jslot == 0) {            // lanes 0..3, one per kq
#pragma unroll
        for (int t = 0; t < 8; t++) {
            msAl[wid][kq * 8 + t] = msAf[t];
            msBl[wid][kq * 8 + t] = msBf[t];
        }
    }
    __syncthreads();                       // epilogue data ready

    if (tid == 0) {
        const float bp0 = bpos[0], bp1 = bpos[1], bp2 = bpos[2];
        float vA0 = 0.f, vA1 = 0.f, vA2 = 0.f, vB0 = 0.f, vB1 = 0.f, vB2 = 0.f;
#pragma unroll
        for (int w = 0; w < 8; w++) {
            vA0 += wacc[w][0]; vA1 += wacc[w][1]; vA2 += wacc[w][2];
            vB0 += wacc[w][3]; vB1 += wacc[w][4]; vB2 += wacc[w][5];
        }
        const float inv = 1.0f / 1023.0f;
        xout[iA * 3 + 0] = xiA0 + (vA0 + bp0 * (SxL[0] - (float)N * xiA0)) * inv;
        xout[iA * 3 + 1] = xiA1 + (vA1 + bp1 * (SxL[1] - (float)N * xiA1)) * inv;
        xout[iA * 3 + 2] = xiA2 + (vA2 + bp2 * (SxL[2] - (float)N * xiA2)) * inv;
        xout[iB * 3 + 0] = xiB0 + (vB0 + bp0 * (SxL[0] - (float)N * xiB0)) * inv;
        xout[iB * 3 + 1] = xiB1 + (vB1 + bp1 * (SxL[1] - (float)N * xiB1)) * inv;
        xout[iB * 3 + 2] = xiB2 + (vB2 + bp2 * (SxL[2] - (float)N * xiB2)) * inv;
    }

    if (LAYER1) {
        // ---- fused h-update + layer-2 A/B projections (R16-verified tail) ----
        float* scr = sbuf;                 // 6848 floats free after main loop
        if (tid < 2 * MD) {                // msum rows with diagonal correction
            const int row = tid >> 5, k = tid & 31;
            const int i = row ? iB : iA;
            const float (*ml)[MD] = row ? msBl : msAl;
            float s = 0.f;
#pragma unroll
            for (int w = 0; w < 8; w++) s += ml[w][k];
            s -= fmaxf(Aap[i * MD + k] + Bbp[i * MD + k], 0.f);   // d2=0 at j==i
            msF[row][k] = s;
        }
        for (int u = tid; u < HD * (HD + MD); u += BLKP) {         // stage wf
            const int o = u / (HD + MD), c = u - o * (HD + MD);
            scr[o * 97 + c] = wf[u];       // max 63*97+95 = 6206 < 6848
        }
        if (tid < 2 * HD) {
            const int row = tid >> 6, d = tid & 63;
            h0r[row][d] = h0[(row ? iB : iA) * HD + d];
        }
        __syncthreads();
        if (tid < 2 * HD) {                // h1 rows (all 64 outputs)
            const int row = tid >> 6, o = tid & 63;
            const float* w = scr + o * 97;
            float s = bf[o];
#pragma unroll
            for (int c = 0; c < HD; c++) s = fmaf(h0r[row][c], w[c], s);
#pragma unroll
            for (int k = 0; k < MD; k++) s = fmaf(msF[row][k], w[HD + k], s);
            h1r[row][o] = fmaxf(s, 0.f);
        }
        __syncthreads();
        for (int u = tid; u < MD * WROW; u += BLKP) scr[u] = wmsg2[u];  // 4128 < 6848
        __syncthreads();
        if (tid < 2 * MD) {                // A2/B2 rows (+ f16 copy of A2)
            const int row = tid >> 5, m = tid & 31;
            const float* wa = scr + m * WROW;
            const float* hr = h1r[row];
            float sa = 0.f, sb = bmsg2[m];
#pragma unroll
            for (int c = 0; c < HD; c++) {
                const float hv = hr[c];
                sa = fmaf(hv, wa[c], sa);
                sb = fmaf(hv, wa[HD + c], sb);
            }
            const int i = row ? iB : iA;
            A2[i * MD + m]  = sa;
            B2[i * MD + m]  = sb;
            A2h[i * MD + m] = (_Float16)sa;
        }
    }
}

// ---------------------------------------------------------------------------
extern "C" void kernel_launch(void* const* d_in, const int* in_sizes, int n_in,
                              void* d_out, int out_size, void* d_ws, size_t ws_size,
                              hipStream_t stream)
{
    const float* pos     = (const float*)d_in[0];
    const float* feat    = (const float*)d_in[1];
    const float* w_msg1  = (const float*)d_in[3];
    const float* b_msg1  = (const float*)d_in[4];
    const float* w_pos1  = (const float*)d_in[5];
    const float* b_pos1  = (const float*)d_in[6];
    const float* w_feat1 = (const float*)d_in[7];
    const float* b_feat1 = (const float*)d_in[8];
    const float* w_msg2  = (const float*)d_in[9];
    const float* b_msg2  = (const float*)d_in[10];
    const float* w_pos2  = (const float*)d_in[11];
    const float* b_pos2  = (const float*)d_in[12];

    float* ws  = (float*)d_ws;
    float* h0  = ws;                 // N*HD
    float* A1  = h0  + N * HD;       // N*MD
    float* B1  = A1  + N * MD;
    float* x1  = B1  + N * MD;       // N*4 (padded)
    float* A2  = x1  + N * 4;
    float* B2  = A2  + N * MD;
    _Float16* Ah1 = (_Float16*)(B2 + N * MD);      // N*MD f16
    _Float16* Ah2 = Ah1 + N * MD;                  // N*MD f16

    k_p0<<<N / 4, BLK, 0, stream>>>(feat, w_msg1, b_msg1, h0, A1, B1, Ah1);
    k_pair<1><<<N / 2, BLKP, 0, stream>>>(pos, A1, Ah1, B1, w_msg1, w_pos1, b_pos1, x1,
                                          h0, w_feat1, b_feat1, w_msg2, b_msg2,
                                          A2, B2, Ah2);
    k_pair<0><<<N / 2, BLKP, 0, stream>>>(x1, A2, Ah2, B2, w_msg2, w_pos2, b_pos2,
                                          (float*)d_out,
                                          nullptr, nullptr, nullptr, nullptr,
                                          nullptr, nullptr, nullptr, nullptr);
}